// Round 4
// baseline (555.950 us; speedup 1.0000x reference)
//
#include <hip/hip_runtime.h>
#include <hip/hip_bf16.h>
#include <math.h>

#define N_NODES 50000
#define N_EDGES 800000
#define IN_DIM 128
#define NEG_SLOPE 0.2f
// HEADS*HID = HEADS*OUT = 256 columns in both GEMMs

__device__ inline unsigned short f2bf(float v) {   // RNE fp32->bf16
    unsigned u = __float_as_uint(v);
    unsigned r = (u + 0x7fffu + ((u >> 16) & 1u)) >> 16;
    return (unsigned short)r;
}
__device__ inline float bf2f(unsigned short b) {
    return __uint_as_float(((unsigned)b) << 16);
}
__device__ inline float lrelu(float v) {
    return v >= 0.f ? v : NEG_SLOPE * v;
}

// ---------------- CSR build ----------------

__global__ void zero_int(int* __restrict__ p, int n) {
    int i = blockIdx.x * blockDim.x + threadIdx.x;
    if (i < n) p[i] = 0;
}

__global__ void hist_kernel(const int* __restrict__ dst, int* __restrict__ cnt) {
    int e = blockIdx.x * blockDim.x + threadIdx.x;
    if (e < N_EDGES) atomicAdd(&cnt[dst[e]], 1);
}

// single-block scan, wave-shuffle based (2 barriers per 1024-tile)
__global__ __launch_bounds__(1024) void scan_kernel(const int* __restrict__ cnt,
                                                    int* __restrict__ off, int n) {
    __shared__ int wsum[16];
    __shared__ int carry_s;
    int tid = threadIdx.x, wid = tid >> 6, lane = tid & 63;
    if (tid == 0) carry_s = 0;
    __syncthreads();
    for (int base = 0; base < n; base += 1024) {
        int i = base + tid;
        int v = (i < n) ? cnt[i] : 0;
        int x = v;
#pragma unroll
        for (int s = 1; s < 64; s <<= 1) {
            int t = __shfl_up(x, s, 64);
            if (lane >= s) x += t;
        }
        if (lane == 63) wsum[wid] = x;
        __syncthreads();
        if (wid == 0 && lane < 16) {
            int w = wsum[lane];
#pragma unroll
            for (int s = 1; s < 16; s <<= 1) {
                int t = __shfl_up(w, s, 64);
                if (lane >= s) w += t;
            }
            wsum[lane] = w;   // inclusive scan of wave sums
        }
        __syncthreads();
        int woff = (wid > 0) ? wsum[wid - 1] : 0;
        int incl = carry_s + woff + x;
        if (i < n) off[i] = incl - v;   // exclusive
        __syncthreads();
        if (tid == 1023) carry_s = incl;
        __syncthreads();
    }
    if (threadIdx.x == 0) off[n] = carry_s;
}

__global__ void copy_int(const int* __restrict__ a, int* __restrict__ b, int n) {
    int i = blockIdx.x * blockDim.x + threadIdx.x;
    if (i < n) b[i] = a[i];
}

__global__ void scatter_kernel(const int* __restrict__ src, const int* __restrict__ dst,
                               int* __restrict__ cur, int* __restrict__ csr_src) {
    int e = blockIdx.x * blockDim.x + threadIdx.x;
    if (e < N_EDGES) {
        int d = dst[e];
        int pos = atomicAdd(&cur[d], 1);
        csr_src[pos] = src[e];
    }
}

// ------- GEMM: C[M,256] = A[M,K]*B[K,256], fp32, 128x128 tile, 8x8/thread -------

template <int K>
__global__ __launch_bounds__(256) void gemm_kernel(const float* __restrict__ A,
                                                   const float* __restrict__ B,
                                                   float* __restrict__ C,
                                                   unsigned short* __restrict__ C16,
                                                   int M) {
    __shared__ float As[16][128];   // k-major
    __shared__ float Bs[16][128];
    int tid = threadIdx.x;
    int row0 = blockIdx.y * 128;
    int col0 = blockIdx.x * 128;
    int tm = tid >> 4, tn = tid & 15;   // 16x16 threads, each 8x8 outputs

    int ar = tid >> 1;           // A loader: row 0..127
    int ak = (tid & 1) * 8;      // A loader: k base {0,8}
    int bk = tid >> 4;           // B loader: k 0..15
    int bc = (tid & 15) * 8;     // B loader: col base

    float acc[8][8] = {};

    for (int kb = 0; kb < K; kb += 16) {
        float4 a0 = make_float4(0.f, 0.f, 0.f, 0.f);
        float4 a1 = a0;
        int arow = row0 + ar;
        if (arow < M) {
            a0 = *reinterpret_cast<const float4*>(&A[(size_t)arow * K + kb + ak]);
            a1 = *reinterpret_cast<const float4*>(&A[(size_t)arow * K + kb + ak + 4]);
        }
        As[ak + 0][ar] = a0.x; As[ak + 1][ar] = a0.y;
        As[ak + 2][ar] = a0.z; As[ak + 3][ar] = a0.w;
        As[ak + 4][ar] = a1.x; As[ak + 5][ar] = a1.y;
        As[ak + 6][ar] = a1.z; As[ak + 7][ar] = a1.w;
        *reinterpret_cast<float4*>(&Bs[bk][bc]) =
            *reinterpret_cast<const float4*>(&B[(size_t)(kb + bk) * 256 + col0 + bc]);
        *reinterpret_cast<float4*>(&Bs[bk][bc + 4]) =
            *reinterpret_cast<const float4*>(&B[(size_t)(kb + bk) * 256 + col0 + bc + 4]);
        __syncthreads();
#pragma unroll
        for (int kk = 0; kk < 16; kk++) {
            float4 x0 = *reinterpret_cast<const float4*>(&As[kk][tm * 8]);
            float4 x1 = *reinterpret_cast<const float4*>(&As[kk][tm * 8 + 4]);
            float4 y0 = *reinterpret_cast<const float4*>(&Bs[kk][tn * 8]);
            float4 y1 = *reinterpret_cast<const float4*>(&Bs[kk][tn * 8 + 4]);
            float xa[8] = {x0.x, x0.y, x0.z, x0.w, x1.x, x1.y, x1.z, x1.w};
            float yb[8] = {y0.x, y0.y, y0.z, y0.w, y1.x, y1.y, y1.z, y1.w};
#pragma unroll
            for (int i = 0; i < 8; i++)
#pragma unroll
                for (int j = 0; j < 8; j++)
                    acc[i][j] += xa[i] * yb[j];
        }
        __syncthreads();
    }
#pragma unroll
    for (int i = 0; i < 8; i++) {
        int r = row0 + tm * 8 + i;
        if (r < M) {
#pragma unroll
            for (int half = 0; half < 2; half++) {
                float4 v = make_float4(acc[i][half * 4 + 0], acc[i][half * 4 + 1],
                                       acc[i][half * 4 + 2], acc[i][half * 4 + 3]);
                *reinterpret_cast<float4*>(&C[(size_t)r * 256 + col0 + tn * 8 + half * 4]) = v;
                ushort4 u;
                u.x = f2bf(v.x); u.y = f2bf(v.y); u.z = f2bf(v.z); u.w = f2bf(v.w);
                *reinterpret_cast<ushort4*>(&C16[(size_t)r * 256 + col0 + tn * 8 + half * 4]) = u;
            }
        }
    }
}

// ---------------- el/er: per-(node,head) attention logits ----------------

__global__ __launch_bounds__(256) void elr_kernel(const float* __restrict__ feat,
                                                  const float* __restrict__ al,
                                                  const float* __restrict__ ar,
                                                  float* __restrict__ el,
                                                  float* __restrict__ er) {
    int n = blockIdx.x;
    int h = threadIdx.x >> 6;
    int lane = threadIdx.x & 63;
    float f = feat[(size_t)n * 256 + h * 64 + lane];
    float pl = f * al[h * 64 + lane];
    float pr = f * ar[h * 64 + lane];
#pragma unroll
    for (int s = 32; s > 0; s >>= 1) {
        pl += __shfl_xor(pl, s, 64);
        pr += __shfl_xor(pr, s, 64);
    }
    if (lane == 0) {
        el[n * 4 + h] = pl;
        er[n * 4 + h] = pr;
    }
}

// ------- aggregation: one wave per node, all 4 heads, batch-4 online softmax -------
// lane l holds features l*4..l*4+3 of the 256-wide row; head h = l>>4.

template <int LAYER>
__global__ __launch_bounds__(256) void agg_kernel(const unsigned short* __restrict__ feat16,
                                                  const float* __restrict__ el,
                                                  const float* __restrict__ er,
                                                  const int* __restrict__ row_off,
                                                  const int* __restrict__ csr_src,
                                                  const float* __restrict__ bias,
                                                  float* __restrict__ out) {
    int n = blockIdx.x * 4 + (threadIdx.x >> 6);   // 12500 blocks * 4 waves = 50000
    int lane = threadIdx.x & 63;
    int h = lane >> 4;
    int js = row_off[n], je = row_off[n + 1];
    float er_nh = er[n * 4 + h];
    float m = -INFINITY, ssum = 0.f;
    float4 acc = make_float4(0.f, 0.f, 0.f, 0.f);
    int j = js;
    for (; j + 3 < je; j += 4) {
        int s0 = csr_src[j], s1 = csr_src[j + 1], s2 = csr_src[j + 2], s3 = csr_src[j + 3];
        ushort4 u0 = *reinterpret_cast<const ushort4*>(&feat16[(size_t)s0 * 256 + lane * 4]);
        ushort4 u1 = *reinterpret_cast<const ushort4*>(&feat16[(size_t)s1 * 256 + lane * 4]);
        ushort4 u2 = *reinterpret_cast<const ushort4*>(&feat16[(size_t)s2 * 256 + lane * 4]);
        ushort4 u3 = *reinterpret_cast<const ushort4*>(&feat16[(size_t)s3 * 256 + lane * 4]);
        float v0 = lrelu(el[s0 * 4 + h] + er_nh);
        float v1 = lrelu(el[s1 * 4 + h] + er_nh);
        float v2 = lrelu(el[s2 * 4 + h] + er_nh);
        float v3 = lrelu(el[s3 * 4 + h] + er_nh);
        float mx = fmaxf(fmaxf(v0, v1), fmaxf(v2, v3));
        float mn = fmaxf(m, mx);
        float sc = __expf(m - mn);     // 0 when m == -inf
        float p0 = __expf(v0 - mn);
        float p1 = __expf(v1 - mn);
        float p2 = __expf(v2 - mn);
        float p3 = __expf(v3 - mn);
        ssum = ssum * sc + ((p0 + p1) + (p2 + p3));
        acc.x = acc.x * sc + (p0 * bf2f(u0.x) + p1 * bf2f(u1.x)) + (p2 * bf2f(u2.x) + p3 * bf2f(u3.x));
        acc.y = acc.y * sc + (p0 * bf2f(u0.y) + p1 * bf2f(u1.y)) + (p2 * bf2f(u2.y) + p3 * bf2f(u3.y));
        acc.z = acc.z * sc + (p0 * bf2f(u0.z) + p1 * bf2f(u1.z)) + (p2 * bf2f(u2.z) + p3 * bf2f(u3.z));
        acc.w = acc.w * sc + (p0 * bf2f(u0.w) + p1 * bf2f(u1.w)) + (p2 * bf2f(u2.w) + p3 * bf2f(u3.w));
        m = mn;
    }
    for (; j < je; j++) {
        int s = csr_src[j];
        ushort4 u = *reinterpret_cast<const ushort4*>(&feat16[(size_t)s * 256 + lane * 4]);
        float val = lrelu(el[s * 4 + h] + er_nh);
        float mn = fmaxf(m, val);
        float sc = __expf(m - mn);
        float p = __expf(val - mn);
        ssum = ssum * sc + p;
        acc.x = acc.x * sc + p * bf2f(u.x);
        acc.y = acc.y * sc + p * bf2f(u.y);
        acc.z = acc.z * sc + p * bf2f(u.z);
        acc.w = acc.w * sc + p * bf2f(u.w);
        m = mn;
    }
    float inv = 1.f / fmaxf(ssum, 1e-9f);
    // bias index: h*64 + (lane&15)*4 + i == lane*4 + i
    float4 res;
    res.x = acc.x * inv + bias[lane * 4 + 0];
    res.y = acc.y * inv + bias[lane * 4 + 1];
    res.z = acc.z * inv + bias[lane * 4 + 2];
    res.w = acc.w * inv + bias[lane * 4 + 3];
    if (LAYER == 1) {
        res.x = res.x > 0.f ? res.x : __expf(res.x) - 1.f;
        res.y = res.y > 0.f ? res.y : __expf(res.y) - 1.f;
        res.z = res.z > 0.f ? res.z : __expf(res.z) - 1.f;
        res.w = res.w > 0.f ? res.w : __expf(res.w) - 1.f;
        *reinterpret_cast<float4*>(&out[(size_t)n * 256 + lane * 4]) = res;
    } else {
        // mean over heads: feature f is held by lanes {f>>2, +16, +32, +48}
#pragma unroll
        for (int mask = 16; mask <= 32; mask <<= 1) {
            res.x += __shfl_xor(res.x, mask, 64);
            res.y += __shfl_xor(res.y, mask, 64);
            res.z += __shfl_xor(res.z, mask, 64);
            res.w += __shfl_xor(res.w, mask, 64);
        }
        if (lane < 16) {
            float4 o = make_float4(res.x * 0.25f, res.y * 0.25f, res.z * 0.25f, res.w * 0.25f);
            *reinterpret_cast<float4*>(&out[(size_t)n * 64 + lane * 4]) = o;
        }
    }
}

// ---------------- launch ----------------

extern "C" void kernel_launch(void* const* d_in, const int* in_sizes, int n_in,
                              void* d_out, int out_size, void* d_ws, size_t ws_size,
                              hipStream_t stream) {
    const float* features = (const float*)d_in[0];
    const int*   src      = (const int*)d_in[1];
    const int*   dst      = (const int*)d_in[2];
    const float* W1       = (const float*)d_in[3];
    const float* al1      = (const float*)d_in[4];
    const float* ar1      = (const float*)d_in[5];
    const float* b1       = (const float*)d_in[6];
    const float* W2       = (const float*)d_in[7];
    const float* al2      = (const float*)d_in[8];
    const float* ar2      = (const float*)d_in[9];
    const float* b2       = (const float*)d_in[10];
    float* out = (float*)d_out;

    char* ws = (char*)d_ws;
    float*          feat    = (float*)(ws);                      // 51,200,000 B
    float*          h1      = (float*)(ws + 51200000);           // 51,200,000 B
    unsigned short* feat16  = (unsigned short*)(ws + 102400000); // 25,600,000 B
    float*          el      = (float*)(ws + 128000000);          //    800,000 B
    float*          er      = (float*)(ws + 128800000);          //    800,000 B
    int*            row_off = (int*)  (ws + 129600000);          //    200,064 B
    int*            cur     = (int*)  (ws + 129800064);          //    200,000 B
    int*            csr     = (int*)  (ws + 130000064);          //  3,200,000 B

    // --- CSR build (graph shared by both layers) ---
    zero_int<<<(N_NODES + 255) / 256, 256, 0, stream>>>(cur, N_NODES);
    hist_kernel<<<(N_EDGES + 255) / 256, 256, 0, stream>>>(dst, cur);
    scan_kernel<<<1, 1024, 0, stream>>>(cur, row_off, N_NODES);
    copy_int<<<(N_NODES + 255) / 256, 256, 0, stream>>>(row_off, cur, N_NODES);
    scatter_kernel<<<(N_EDGES + 255) / 256, 256, 0, stream>>>(src, dst, cur, csr);

    dim3 gemm_grid(2, (N_NODES + 127) / 128);

    // --- layer 1 ---
    gemm_kernel<IN_DIM><<<gemm_grid, 256, 0, stream>>>(features, W1, feat, feat16, N_NODES);
    elr_kernel<<<N_NODES, 256, 0, stream>>>(feat, al1, ar1, el, er);
    agg_kernel<1><<<12500, 256, 0, stream>>>(feat16, el, er, row_off, csr, b1, h1);

    // --- layer 2 ---
    gemm_kernel<256><<<gemm_grid, 256, 0, stream>>>(h1, W2, feat, feat16, N_NODES);
    elr_kernel<<<N_NODES, 256, 0, stream>>>(feat, al2, ar2, el, er);
    agg_kernel<2><<<12500, 256, 0, stream>>>(feat16, el, er, row_off, csr, b2, out);
}

// Round 5
// 481.325 us; speedup vs baseline: 1.1550x; 1.1550x over previous
//
#include <hip/hip_runtime.h>
#include <hip/hip_bf16.h>
#include <math.h>

#define N_NODES 50000
#define N_EDGES 800000
#define IN_DIM 128
#define NEG_SLOPE 0.2f
// HEADS*HID = HEADS*OUT = 256 columns in both GEMMs

typedef __attribute__((ext_vector_type(8))) short s16x8;
typedef __attribute__((ext_vector_type(4))) float f32x4;

__device__ inline unsigned short f2bf(float v) {   // RNE fp32->bf16
    unsigned u = __float_as_uint(v);
    unsigned r = (u + 0x7fffu + ((u >> 16) & 1u)) >> 16;
    return (unsigned short)r;
}
__device__ inline float bf2f(unsigned short b) {
    return __uint_as_float(((unsigned)b) << 16);
}
__device__ inline float lrelu(float v) {
    return v >= 0.f ? v : NEG_SLOPE * v;
}

// ---------------- CSR build ----------------

__global__ void zero_int(int* __restrict__ p, int n) {
    int i = blockIdx.x * blockDim.x + threadIdx.x;
    if (i < n) p[i] = 0;
}

__global__ void hist_kernel(const int* __restrict__ dst, int* __restrict__ cnt) {
    int e = blockIdx.x * blockDim.x + threadIdx.x;
    if (e < N_EDGES) atomicAdd(&cnt[dst[e]], 1);
}

// single-block scan, wave-shuffle based (2 barriers per 1024-tile)
__global__ __launch_bounds__(1024) void scan_kernel(const int* __restrict__ cnt,
                                                    int* __restrict__ off, int n) {
    __shared__ int wsum[16];
    __shared__ int carry_s;
    int tid = threadIdx.x, wid = tid >> 6, lane = tid & 63;
    if (tid == 0) carry_s = 0;
    __syncthreads();
    for (int base = 0; base < n; base += 1024) {
        int i = base + tid;
        int v = (i < n) ? cnt[i] : 0;
        int x = v;
#pragma unroll
        for (int s = 1; s < 64; s <<= 1) {
            int t = __shfl_up(x, s, 64);
            if (lane >= s) x += t;
        }
        if (lane == 63) wsum[wid] = x;
        __syncthreads();
        if (wid == 0 && lane < 16) {
            int w = wsum[lane];
#pragma unroll
            for (int s = 1; s < 16; s <<= 1) {
                int t = __shfl_up(w, s, 64);
                if (lane >= s) w += t;
            }
            wsum[lane] = w;   // inclusive scan of wave sums
        }
        __syncthreads();
        int woff = (wid > 0) ? wsum[wid - 1] : 0;
        int incl = carry_s + woff + x;
        if (i < n) off[i] = incl - v;   // exclusive
        __syncthreads();
        if (tid == 1023) carry_s = incl;
        __syncthreads();
    }
    if (threadIdx.x == 0) off[n] = carry_s;
}

__global__ void copy_int(const int* __restrict__ a, int* __restrict__ b, int n) {
    int i = blockIdx.x * blockDim.x + threadIdx.x;
    if (i < n) b[i] = a[i];
}

__global__ void scatter_kernel(const int* __restrict__ src, const int* __restrict__ dst,
                               int* __restrict__ cur, int* __restrict__ csr_src) {
    int e = blockIdx.x * blockDim.x + threadIdx.x;
    if (e < N_EDGES) {
        int d = dst[e];
        int pos = atomicAdd(&cur[d], 1);
        csr_src[pos] = src[e];
    }
}

// ---------------- split fp32 -> bf16 hi/lo ----------------

__global__ void split_feat(const float* __restrict__ in, unsigned short* __restrict__ hi,
                           unsigned short* __restrict__ lo, int n) {
    int i = blockIdx.x * blockDim.x + threadIdx.x;
    if (i < n) {
        float v = in[i];
        unsigned short h = f2bf(v);
        hi[i] = h;
        lo[i] = f2bf(v - bf2f(h));
    }
}

// W [K x 256] fp32 -> Bt hi/lo [256 x K] bf16
template <int K>
__global__ void split_wt(const float* __restrict__ W, unsigned short* __restrict__ Bth,
                         unsigned short* __restrict__ Btl) {
    int k = blockIdx.x;        // 0..K-1
    int c = threadIdx.x;       // 0..255
    float v = W[(size_t)k * 256 + c];
    unsigned short h = f2bf(v);
    Bth[(size_t)c * K + k] = h;
    Btl[(size_t)c * K + k] = f2bf(v - bf2f(h));
}

// ------- MFMA GEMM: C[M,256] = (Ahi+Alo)[M,K] * (Bhi+Blo)[K,256] -------
// Bt is B transposed [256][K]. 64x64 block, 4 waves, wave = 32x32 (2x2 frags).
// frag: lane l holds row/col (l&15), k = (l>>4)*8 + 0..7 (contiguous 16B).
// C/D: col = lane&15, row = (lane>>4)*4 + reg  (learn_hip m89).

template <int K>
__global__ __launch_bounds__(256) void mfma_gemm(const unsigned short* __restrict__ Ahi,
                                                 const unsigned short* __restrict__ Alo,
                                                 const unsigned short* __restrict__ Bth,
                                                 const unsigned short* __restrict__ Btl,
                                                 float* __restrict__ C,
                                                 unsigned short* __restrict__ C16,
                                                 int M) {
    int wave = threadIdx.x >> 6;
    int lane = threadIdx.x & 63;
    int wm = wave >> 1, wn = wave & 1;
    int row0 = blockIdx.y * 64 + wm * 32;
    int col0 = blockIdx.x * 64 + wn * 32;
    int r = lane & 15;
    int kg = (lane >> 4) * 8;

    f32x4 acc[2][2] = {};

    int rowA0 = row0 + r;        if (rowA0 >= M) rowA0 = M - 1;
    int rowA1 = row0 + 16 + r;   if (rowA1 >= M) rowA1 = M - 1;
    const size_t a0 = (size_t)rowA0 * K + kg;
    const size_t a1 = (size_t)rowA1 * K + kg;
    const size_t b0 = (size_t)(col0 + r) * K + kg;
    const size_t b1 = (size_t)(col0 + 16 + r) * K + kg;

    for (int kb = 0; kb < K; kb += 32) {
        s16x8 ah0 = *reinterpret_cast<const s16x8*>(&Ahi[a0 + kb]);
        s16x8 ah1 = *reinterpret_cast<const s16x8*>(&Ahi[a1 + kb]);
        s16x8 al0 = *reinterpret_cast<const s16x8*>(&Alo[a0 + kb]);
        s16x8 al1 = *reinterpret_cast<const s16x8*>(&Alo[a1 + kb]);
        s16x8 bh0 = *reinterpret_cast<const s16x8*>(&Bth[b0 + kb]);
        s16x8 bh1 = *reinterpret_cast<const s16x8*>(&Bth[b1 + kb]);
        s16x8 bl0 = *reinterpret_cast<const s16x8*>(&Btl[b0 + kb]);
        s16x8 bl1 = *reinterpret_cast<const s16x8*>(&Btl[b1 + kb]);

        acc[0][0] = __builtin_amdgcn_mfma_f32_16x16x32_bf16(ah0, bh0, acc[0][0], 0, 0, 0);
        acc[0][1] = __builtin_amdgcn_mfma_f32_16x16x32_bf16(ah0, bh1, acc[0][1], 0, 0, 0);
        acc[1][0] = __builtin_amdgcn_mfma_f32_16x16x32_bf16(ah1, bh0, acc[1][0], 0, 0, 0);
        acc[1][1] = __builtin_amdgcn_mfma_f32_16x16x32_bf16(ah1, bh1, acc[1][1], 0, 0, 0);

        acc[0][0] = __builtin_amdgcn_mfma_f32_16x16x32_bf16(ah0, bl0, acc[0][0], 0, 0, 0);
        acc[0][1] = __builtin_amdgcn_mfma_f32_16x16x32_bf16(ah0, bl1, acc[0][1], 0, 0, 0);
        acc[1][0] = __builtin_amdgcn_mfma_f32_16x16x32_bf16(ah1, bl0, acc[1][0], 0, 0, 0);
        acc[1][1] = __builtin_amdgcn_mfma_f32_16x16x32_bf16(ah1, bl1, acc[1][1], 0, 0, 0);

        acc[0][0] = __builtin_amdgcn_mfma_f32_16x16x32_bf16(al0, bh0, acc[0][0], 0, 0, 0);
        acc[0][1] = __builtin_amdgcn_mfma_f32_16x16x32_bf16(al0, bh1, acc[0][1], 0, 0, 0);
        acc[1][0] = __builtin_amdgcn_mfma_f32_16x16x32_bf16(al1, bh0, acc[1][0], 0, 0, 0);
        acc[1][1] = __builtin_amdgcn_mfma_f32_16x16x32_bf16(al1, bh1, acc[1][1], 0, 0, 0);
    }

#pragma unroll
    for (int mi = 0; mi < 2; mi++) {
#pragma unroll
        for (int ni = 0; ni < 2; ni++) {
            int col = col0 + ni * 16 + r;
#pragma unroll
            for (int reg = 0; reg < 4; reg++) {
                int row = row0 + mi * 16 + (lane >> 4) * 4 + reg;
                if (row < M) {
                    float v = acc[mi][ni][reg];
                    C[(size_t)row * 256 + col] = v;
                    C16[(size_t)row * 256 + col] = f2bf(v);
                }
            }
        }
    }
}

// ---------------- el/er: per-(node,head) attention logits ----------------

__global__ __launch_bounds__(256) void elr_kernel(const float* __restrict__ feat,
                                                  const float* __restrict__ al,
                                                  const float* __restrict__ ar,
                                                  float* __restrict__ el,
                                                  float* __restrict__ er) {
    int n = blockIdx.x;
    int h = threadIdx.x >> 6;
    int lane = threadIdx.x & 63;
    float f = feat[(size_t)n * 256 + h * 64 + lane];
    float pl = f * al[h * 64 + lane];
    float pr = f * ar[h * 64 + lane];
#pragma unroll
    for (int s = 32; s > 0; s >>= 1) {
        pl += __shfl_xor(pl, s, 64);
        pr += __shfl_xor(pr, s, 64);
    }
    if (lane == 0) {
        el[n * 4 + h] = pl;
        er[n * 4 + h] = pr;
    }
}

// ------- aggregation: one wave per node, all 4 heads, batch-4 online softmax -------
// lane l holds features l*4..l*4+3 of the 256-wide row; head h = l>>4.
// LAYER 1: writes elu(res) as bf16 hi/lo (input to GEMM2). LAYER 2: head-mean -> fp32 out.

template <int LAYER>
__global__ __launch_bounds__(256) void agg_kernel(const unsigned short* __restrict__ feat16,
                                                  const float* __restrict__ el,
                                                  const float* __restrict__ er,
                                                  const int* __restrict__ row_off,
                                                  const int* __restrict__ csr_src,
                                                  const float* __restrict__ bias,
                                                  unsigned short* __restrict__ out_hi,
                                                  unsigned short* __restrict__ out_lo,
                                                  float* __restrict__ outf) {
    int n = blockIdx.x * 4 + (threadIdx.x >> 6);   // 12500 blocks * 4 waves = 50000
    int lane = threadIdx.x & 63;
    int h = lane >> 4;
    int js = row_off[n], je = row_off[n + 1];
    float er_nh = er[n * 4 + h];
    float m = -INFINITY, ssum = 0.f;
    float4 acc = make_float4(0.f, 0.f, 0.f, 0.f);
    int j = js;
    for (; j + 3 < je; j += 4) {
        int s0 = csr_src[j], s1 = csr_src[j + 1], s2 = csr_src[j + 2], s3 = csr_src[j + 3];
        ushort4 u0 = *reinterpret_cast<const ushort4*>(&feat16[(size_t)s0 * 256 + lane * 4]);
        ushort4 u1 = *reinterpret_cast<const ushort4*>(&feat16[(size_t)s1 * 256 + lane * 4]);
        ushort4 u2 = *reinterpret_cast<const ushort4*>(&feat16[(size_t)s2 * 256 + lane * 4]);
        ushort4 u3 = *reinterpret_cast<const ushort4*>(&feat16[(size_t)s3 * 256 + lane * 4]);
        float v0 = lrelu(el[s0 * 4 + h] + er_nh);
        float v1 = lrelu(el[s1 * 4 + h] + er_nh);
        float v2 = lrelu(el[s2 * 4 + h] + er_nh);
        float v3 = lrelu(el[s3 * 4 + h] + er_nh);
        float mx = fmaxf(fmaxf(v0, v1), fmaxf(v2, v3));
        float mn = fmaxf(m, mx);
        float sc = __expf(m - mn);     // 0 when m == -inf
        float p0 = __expf(v0 - mn);
        float p1 = __expf(v1 - mn);
        float p2 = __expf(v2 - mn);
        float p3 = __expf(v3 - mn);
        ssum = ssum * sc + ((p0 + p1) + (p2 + p3));
        acc.x = acc.x * sc + (p0 * bf2f(u0.x) + p1 * bf2f(u1.x)) + (p2 * bf2f(u2.x) + p3 * bf2f(u3.x));
        acc.y = acc.y * sc + (p0 * bf2f(u0.y) + p1 * bf2f(u1.y)) + (p2 * bf2f(u2.y) + p3 * bf2f(u3.y));
        acc.z = acc.z * sc + (p0 * bf2f(u0.z) + p1 * bf2f(u1.z)) + (p2 * bf2f(u2.z) + p3 * bf2f(u3.z));
        acc.w = acc.w * sc + (p0 * bf2f(u0.w) + p1 * bf2f(u1.w)) + (p2 * bf2f(u2.w) + p3 * bf2f(u3.w));
        m = mn;
    }
    for (; j < je; j++) {
        int s = csr_src[j];
        ushort4 u = *reinterpret_cast<const ushort4*>(&feat16[(size_t)s * 256 + lane * 4]);
        float val = lrelu(el[s * 4 + h] + er_nh);
        float mn = fmaxf(m, val);
        float sc = __expf(m - mn);
        float p = __expf(val - mn);
        ssum = ssum * sc + p;
        acc.x = acc.x * sc + p * bf2f(u.x);
        acc.y = acc.y * sc + p * bf2f(u.y);
        acc.z = acc.z * sc + p * bf2f(u.z);
        acc.w = acc.w * sc + p * bf2f(u.w);
        m = mn;
    }
    float inv = 1.f / fmaxf(ssum, 1e-9f);
    // bias index: h*64 + (lane&15)*4 + i == lane*4 + i
    float4 res;
    res.x = acc.x * inv + bias[lane * 4 + 0];
    res.y = acc.y * inv + bias[lane * 4 + 1];
    res.z = acc.z * inv + bias[lane * 4 + 2];
    res.w = acc.w * inv + bias[lane * 4 + 3];
    if (LAYER == 1) {
        res.x = res.x > 0.f ? res.x : __expf(res.x) - 1.f;
        res.y = res.y > 0.f ? res.y : __expf(res.y) - 1.f;
        res.z = res.z > 0.f ? res.z : __expf(res.z) - 1.f;
        res.w = res.w > 0.f ? res.w : __expf(res.w) - 1.f;
        ushort4 hz, lz;
        hz.x = f2bf(res.x); lz.x = f2bf(res.x - bf2f(hz.x));
        hz.y = f2bf(res.y); lz.y = f2bf(res.y - bf2f(hz.y));
        hz.z = f2bf(res.z); lz.z = f2bf(res.z - bf2f(hz.z));
        hz.w = f2bf(res.w); lz.w = f2bf(res.w - bf2f(hz.w));
        *reinterpret_cast<ushort4*>(&out_hi[(size_t)n * 256 + lane * 4]) = hz;
        *reinterpret_cast<ushort4*>(&out_lo[(size_t)n * 256 + lane * 4]) = lz;
    } else {
        // mean over heads: feature f is held by lanes {f>>2, +16, +32, +48}
#pragma unroll
        for (int mask = 16; mask <= 32; mask <<= 1) {
            res.x += __shfl_xor(res.x, mask, 64);
            res.y += __shfl_xor(res.y, mask, 64);
            res.z += __shfl_xor(res.z, mask, 64);
            res.w += __shfl_xor(res.w, mask, 64);
        }
        if (lane < 16) {
            float4 o = make_float4(res.x * 0.25f, res.y * 0.25f, res.z * 0.25f, res.w * 0.25f);
            *reinterpret_cast<float4*>(&outf[(size_t)n * 64 + lane * 4]) = o;
        }
    }
}

// ---------------- launch ----------------

extern "C" void kernel_launch(void* const* d_in, const int* in_sizes, int n_in,
                              void* d_out, int out_size, void* d_ws, size_t ws_size,
                              hipStream_t stream) {
    const float* features = (const float*)d_in[0];
    const int*   src      = (const int*)d_in[1];
    const int*   dst      = (const int*)d_in[2];
    const float* W1       = (const float*)d_in[3];
    const float* al1      = (const float*)d_in[4];
    const float* ar1      = (const float*)d_in[5];
    const float* b1       = (const float*)d_in[6];
    const float* W2       = (const float*)d_in[7];
    const float* al2      = (const float*)d_in[8];
    const float* ar2      = (const float*)d_in[9];
    const float* b2       = (const float*)d_in[10];
    float* out = (float*)d_out;

    char* ws = (char*)d_ws;
    float*          feat    = (float*)(ws);                      // 51,200,000 B fp32 [50000x256]
    unsigned short* feat16  = (unsigned short*)(ws + 51200000);  // 25,600,000 B
    unsigned short* h1_hi   = (unsigned short*)(ws + 76800000);  // 25,600,000 B (union: fA_hi/fA_lo)
    unsigned short* h1_lo   = (unsigned short*)(ws + 102400000); // 25,600,000 B
    unsigned short* fA_hi   = (unsigned short*)(ws + 76800000);  // 12,800,000 B [50000x128] (dead before h1 written)
    unsigned short* fA_lo   = (unsigned short*)(ws + 89600000);  // 12,800,000 B
    unsigned short* Bt1_hi  = (unsigned short*)(ws + 128000000); //     65,536 B
    unsigned short* Bt1_lo  = (unsigned short*)(ws + 128065536); //     65,536 B
    unsigned short* Bt2_hi  = (unsigned short*)(ws + 128131072); //    131,072 B
    unsigned short* Bt2_lo  = (unsigned short*)(ws + 128262144); //    131,072 B
    float*          el      = (float*)(ws + 128393216);          //    800,000 B
    float*          er      = (float*)(ws + 129193216);          //    800,000 B
    int*            row_off = (int*)  (ws + 129993216);          //    200,064 B
    int*            cur     = (int*)  (ws + 130193280);          //    200,000 B
    int*            csr     = (int*)  (ws + 130393280);          //  3,200,000 B  (end ~133.6 MB)

    // --- CSR build (graph shared by both layers) ---
    zero_int<<<(N_NODES + 255) / 256, 256, 0, stream>>>(cur, N_NODES);
    hist_kernel<<<(N_EDGES + 255) / 256, 256, 0, stream>>>(dst, cur);
    scan_kernel<<<1, 1024, 0, stream>>>(cur, row_off, N_NODES);
    copy_int<<<(N_NODES + 255) / 256, 256, 0, stream>>>(row_off, cur, N_NODES);
    scatter_kernel<<<(N_EDGES + 255) / 256, 256, 0, stream>>>(src, dst, cur, csr);

    // --- input splits ---
    split_feat<<<(N_NODES * IN_DIM + 255) / 256, 256, 0, stream>>>(features, fA_hi, fA_lo, N_NODES * IN_DIM);
    split_wt<IN_DIM><<<IN_DIM, 256, 0, stream>>>(W1, Bt1_hi, Bt1_lo);
    split_wt<256><<<256, 256, 0, stream>>>(W2, Bt2_hi, Bt2_lo);

    dim3 gemm_grid(4, (N_NODES + 63) / 64);

    // --- layer 1 ---
    mfma_gemm<IN_DIM><<<gemm_grid, 256, 0, stream>>>(fA_hi, fA_lo, Bt1_hi, Bt1_lo, feat, feat16, N_NODES);
    elr_kernel<<<N_NODES, 256, 0, stream>>>(feat, al1, ar1, el, er);
    agg_kernel<1><<<12500, 256, 0, stream>>>(feat16, el, er, row_off, csr, b1, h1_hi, h1_lo, nullptr);

    // --- layer 2 ---
    mfma_gemm<256><<<gemm_grid, 256, 0, stream>>>(h1_hi, h1_lo, Bt2_hi, Bt2_lo, feat, feat16, N_NODES);
    elr_kernel<<<N_NODES, 256, 0, stream>>>(feat, al2, ar2, el, er);
    agg_kernel<2><<<12500, 256, 0, stream>>>(feat16, el, er, row_off, csr, b2, nullptr, nullptr, out);
}

// Round 6
// 478.989 us; speedup vs baseline: 1.1607x; 1.0049x over previous
//
#include <hip/hip_runtime.h>
#include <hip/hip_bf16.h>
#include <math.h>

#define N_NODES 50000
#define N_EDGES 800000
#define IN_DIM 128
#define NEG_SLOPE 0.2f
// HEADS*HID = HEADS*OUT = 256 columns in both GEMMs

typedef __attribute__((ext_vector_type(8))) short s16x8;
typedef __attribute__((ext_vector_type(4))) float f32x4;

__device__ inline unsigned short f2bf(float v) {   // RNE fp32->bf16
    unsigned u = __float_as_uint(v);
    unsigned r = (u + 0x7fffu + ((u >> 16) & 1u)) >> 16;
    return (unsigned short)r;
}
__device__ inline float bf2f(unsigned short b) {
    return __uint_as_float(((unsigned)b) << 16);
}
__device__ inline float lrelu(float v) {
    return v >= 0.f ? v : NEG_SLOPE * v;
}

// ---------------- CSR build ----------------

__global__ void zero_int(int* __restrict__ p, int n) {
    int i = blockIdx.x * blockDim.x + threadIdx.x;
    if (i < n) p[i] = 0;
}

__global__ void hist_kernel(const int* __restrict__ dst, int* __restrict__ cnt) {
    int e = blockIdx.x * blockDim.x + threadIdx.x;
    if (e < N_EDGES) atomicAdd(&cnt[dst[e]], 1);
}

// single-block scan, wave-shuffle based (2 barriers per 1024-tile)
__global__ __launch_bounds__(1024) void scan_kernel(const int* __restrict__ cnt,
                                                    int* __restrict__ off, int n) {
    __shared__ int wsum[16];
    __shared__ int carry_s;
    int tid = threadIdx.x, wid = tid >> 6, lane = tid & 63;
    if (tid == 0) carry_s = 0;
    __syncthreads();
    for (int base = 0; base < n; base += 1024) {
        int i = base + tid;
        int v = (i < n) ? cnt[i] : 0;
        int x = v;
#pragma unroll
        for (int s = 1; s < 64; s <<= 1) {
            int t = __shfl_up(x, s, 64);
            if (lane >= s) x += t;
        }
        if (lane == 63) wsum[wid] = x;
        __syncthreads();
        if (wid == 0 && lane < 16) {
            int w = wsum[lane];
#pragma unroll
            for (int s = 1; s < 16; s <<= 1) {
                int t = __shfl_up(w, s, 64);
                if (lane >= s) w += t;
            }
            wsum[lane] = w;   // inclusive scan of wave sums
        }
        __syncthreads();
        int woff = (wid > 0) ? wsum[wid - 1] : 0;
        int incl = carry_s + woff + x;
        if (i < n) off[i] = incl - v;   // exclusive
        __syncthreads();
        if (tid == 1023) carry_s = incl;
        __syncthreads();
    }
    if (threadIdx.x == 0) off[n] = carry_s;
}

__global__ void copy_int(const int* __restrict__ a, int* __restrict__ b, int n) {
    int i = blockIdx.x * blockDim.x + threadIdx.x;
    if (i < n) b[i] = a[i];
}

__global__ void scatter_kernel(const int* __restrict__ src, const int* __restrict__ dst,
                               int* __restrict__ cur, int* __restrict__ csr_src) {
    int e = blockIdx.x * blockDim.x + threadIdx.x;
    if (e < N_EDGES) {
        int d = dst[e];
        int pos = atomicAdd(&cur[d], 1);
        csr_src[pos] = src[e];
    }
}

// ---------------- split fp32 -> bf16 hi/lo ----------------

__global__ void split_feat(const float* __restrict__ in, unsigned short* __restrict__ hi,
                           unsigned short* __restrict__ lo, int n) {
    int i = blockIdx.x * blockDim.x + threadIdx.x;
    if (i < n) {
        float v = in[i];
        unsigned short h = f2bf(v);
        hi[i] = h;
        lo[i] = f2bf(v - bf2f(h));
    }
}

// W [K x 256] fp32 -> Bt hi/lo [256 x K] bf16
template <int K>
__global__ void split_wt(const float* __restrict__ W, unsigned short* __restrict__ Bth,
                         unsigned short* __restrict__ Btl) {
    int k = blockIdx.x;        // 0..K-1
    int c = threadIdx.x;       // 0..255
    float v = W[(size_t)k * 256 + c];
    unsigned short h = f2bf(v);
    Bth[(size_t)c * K + k] = h;
    Btl[(size_t)c * K + k] = f2bf(v - bf2f(h));
}

// ------- MFMA GEMM: C[M,256] = (Ahi+Alo)[M,K] * (Bhi+Blo)[K,256] -------
// Block: 64 rows x ALL 256 cols (4 strips of 64), 4 waves as 2x2 over 64x64.
// A fragments loaded once per k-step, reused across the 4 strips in registers;
// next k-step's A prefetched (reg-staged). B is L2-resident, loaded per strip.
// frag: lane l holds row/col (l&15), k = (l>>4)*8 + 0..7 (contiguous 16B).
// C/D: col = lane&15, row = (lane>>4)*4 + reg  (learn_hip m89).
// Output: bf16 hi + lo (no fp32 C).

template <int K>
__global__ __launch_bounds__(256) void mfma_gemm(const unsigned short* __restrict__ Ahi,
                                                 const unsigned short* __restrict__ Alo,
                                                 const unsigned short* __restrict__ Bth,
                                                 const unsigned short* __restrict__ Btl,
                                                 unsigned short* __restrict__ Chi,
                                                 unsigned short* __restrict__ Clo,
                                                 int M) {
    int wave = threadIdx.x >> 6;
    int lane = threadIdx.x & 63;
    int wm = wave >> 1, wn = wave & 1;
    int row0 = blockIdx.x * 64 + wm * 32;
    int r = lane & 15;
    int kg = (lane >> 4) * 8;

    f32x4 acc[4][2][2] = {};   // [strip][mi][ni]

    int rowA0 = row0 + r;        if (rowA0 >= M) rowA0 = M - 1;
    int rowA1 = row0 + 16 + r;   if (rowA1 >= M) rowA1 = M - 1;
    const unsigned short* pa0h = Ahi + (size_t)rowA0 * K + kg;
    const unsigned short* pa1h = Ahi + (size_t)rowA1 * K + kg;
    const unsigned short* pa0l = Alo + (size_t)rowA0 * K + kg;
    const unsigned short* pa1l = Alo + (size_t)rowA1 * K + kg;
    const unsigned short* pbh  = Bth + (size_t)(wn * 32 + r) * K + kg;
    const unsigned short* pbl  = Btl + (size_t)(wn * 32 + r) * K + kg;

    s16x8 ah0 = *reinterpret_cast<const s16x8*>(pa0h);
    s16x8 ah1 = *reinterpret_cast<const s16x8*>(pa1h);
    s16x8 al0 = *reinterpret_cast<const s16x8*>(pa0l);
    s16x8 al1 = *reinterpret_cast<const s16x8*>(pa1l);

    for (int kb = 0; kb < K; kb += 32) {
        // prefetch next k-step's A (last iter over-reads into adjacent ws; unused)
        s16x8 nah0 = *reinterpret_cast<const s16x8*>(pa0h + kb + 32);
        s16x8 nah1 = *reinterpret_cast<const s16x8*>(pa1h + kb + 32);
        s16x8 nal0 = *reinterpret_cast<const s16x8*>(pa0l + kb + 32);
        s16x8 nal1 = *reinterpret_cast<const s16x8*>(pa1l + kb + 32);
#pragma unroll
        for (int s = 0; s < 4; s++) {
            const size_t boff = (size_t)(s * 64) * K + kb;
            s16x8 bh0 = *reinterpret_cast<const s16x8*>(pbh + boff);
            s16x8 bh1 = *reinterpret_cast<const s16x8*>(pbh + boff + (size_t)16 * K);
            s16x8 bl0 = *reinterpret_cast<const s16x8*>(pbl + boff);
            s16x8 bl1 = *reinterpret_cast<const s16x8*>(pbl + boff + (size_t)16 * K);

            acc[s][0][0] = __builtin_amdgcn_mfma_f32_16x16x32_bf16(ah0, bh0, acc[s][0][0], 0, 0, 0);
            acc[s][0][1] = __builtin_amdgcn_mfma_f32_16x16x32_bf16(ah0, bh1, acc[s][0][1], 0, 0, 0);
            acc[s][1][0] = __builtin_amdgcn_mfma_f32_16x16x32_bf16(ah1, bh0, acc[s][1][0], 0, 0, 0);
            acc[s][1][1] = __builtin_amdgcn_mfma_f32_16x16x32_bf16(ah1, bh1, acc[s][1][1], 0, 0, 0);

            acc[s][0][0] = __builtin_amdgcn_mfma_f32_16x16x32_bf16(ah0, bl0, acc[s][0][0], 0, 0, 0);
            acc[s][0][1] = __builtin_amdgcn_mfma_f32_16x16x32_bf16(ah0, bl1, acc[s][0][1], 0, 0, 0);
            acc[s][1][0] = __builtin_amdgcn_mfma_f32_16x16x32_bf16(ah1, bl0, acc[s][1][0], 0, 0, 0);
            acc[s][1][1] = __builtin_amdgcn_mfma_f32_16x16x32_bf16(ah1, bl1, acc[s][1][1], 0, 0, 0);

            acc[s][0][0] = __builtin_amdgcn_mfma_f32_16x16x32_bf16(al0, bh0, acc[s][0][0], 0, 0, 0);
            acc[s][0][1] = __builtin_amdgcn_mfma_f32_16x16x32_bf16(al0, bh1, acc[s][0][1], 0, 0, 0);
            acc[s][1][0] = __builtin_amdgcn_mfma_f32_16x16x32_bf16(al1, bh0, acc[s][1][0], 0, 0, 0);
            acc[s][1][1] = __builtin_amdgcn_mfma_f32_16x16x32_bf16(al1, bh1, acc[s][1][1], 0, 0, 0);
        }
        ah0 = nah0; ah1 = nah1; al0 = nal0; al1 = nal1;
    }

#pragma unroll
    for (int s = 0; s < 4; s++) {
#pragma unroll
        for (int mi = 0; mi < 2; mi++) {
#pragma unroll
            for (int ni = 0; ni < 2; ni++) {
                int col = s * 64 + wn * 32 + ni * 16 + r;
#pragma unroll
                for (int reg = 0; reg < 4; reg++) {
                    int row = row0 + mi * 16 + (lane >> 4) * 4 + reg;
                    if (row < M) {
                        float v = acc[s][mi][ni][reg];
                        unsigned short hz = f2bf(v);
                        Chi[(size_t)row * 256 + col] = hz;
                        Clo[(size_t)row * 256 + col] = f2bf(v - bf2f(hz));
                    }
                }
            }
        }
    }
}

// ---------------- el/er: per-(node,head) attention logits ----------------
// feat reconstructed as hi + lo (== fp32 GEMM result to bf16-pair precision)

__global__ __launch_bounds__(256) void elr_kernel(const unsigned short* __restrict__ fhi,
                                                  const unsigned short* __restrict__ flo,
                                                  const float* __restrict__ al,
                                                  const float* __restrict__ ar,
                                                  float* __restrict__ el,
                                                  float* __restrict__ er) {
    int n = blockIdx.x;
    int h = threadIdx.x >> 6;
    int lane = threadIdx.x & 63;
    size_t idx = (size_t)n * 256 + h * 64 + lane;
    float f = bf2f(fhi[idx]) + bf2f(flo[idx]);
    float pl = f * al[h * 64 + lane];
    float pr = f * ar[h * 64 + lane];
#pragma unroll
    for (int s = 32; s > 0; s >>= 1) {
        pl += __shfl_xor(pl, s, 64);
        pr += __shfl_xor(pr, s, 64);
    }
    if (lane == 0) {
        el[n * 4 + h] = pl;
        er[n * 4 + h] = pr;
    }
}

// ------- aggregation: one wave per node, all 4 heads, batch-4 online softmax -------
// lane l holds features l*4..l*4+3 of the 256-wide row; head h = l>>4.
// LAYER 1: writes elu(res) as bf16 hi/lo (input to GEMM2). LAYER 2: head-mean -> fp32 out.

template <int LAYER>
__global__ __launch_bounds__(256) void agg_kernel(const unsigned short* __restrict__ feat16,
                                                  const float* __restrict__ el,
                                                  const float* __restrict__ er,
                                                  const int* __restrict__ row_off,
                                                  const int* __restrict__ csr_src,
                                                  const float* __restrict__ bias,
                                                  unsigned short* __restrict__ out_hi,
                                                  unsigned short* __restrict__ out_lo,
                                                  float* __restrict__ outf) {
    int n = blockIdx.x * 4 + (threadIdx.x >> 6);   // 12500 blocks * 4 waves = 50000
    int lane = threadIdx.x & 63;
    int h = lane >> 4;
    int js = row_off[n], je = row_off[n + 1];
    float er_nh = er[n * 4 + h];
    float m = -INFINITY, ssum = 0.f;
    float4 acc = make_float4(0.f, 0.f, 0.f, 0.f);
    int j = js;
    for (; j + 3 < je; j += 4) {
        int s0 = csr_src[j], s1 = csr_src[j + 1], s2 = csr_src[j + 2], s3 = csr_src[j + 3];
        ushort4 u0 = *reinterpret_cast<const ushort4*>(&feat16[(size_t)s0 * 256 + lane * 4]);
        ushort4 u1 = *reinterpret_cast<const ushort4*>(&feat16[(size_t)s1 * 256 + lane * 4]);
        ushort4 u2 = *reinterpret_cast<const ushort4*>(&feat16[(size_t)s2 * 256 + lane * 4]);
        ushort4 u3 = *reinterpret_cast<const ushort4*>(&feat16[(size_t)s3 * 256 + lane * 4]);
        float v0 = lrelu(el[s0 * 4 + h] + er_nh);
        float v1 = lrelu(el[s1 * 4 + h] + er_nh);
        float v2 = lrelu(el[s2 * 4 + h] + er_nh);
        float v3 = lrelu(el[s3 * 4 + h] + er_nh);
        float mx = fmaxf(fmaxf(v0, v1), fmaxf(v2, v3));
        float mn = fmaxf(m, mx);
        float sc = __expf(m - mn);     // 0 when m == -inf
        float p0 = __expf(v0 - mn);
        float p1 = __expf(v1 - mn);
        float p2 = __expf(v2 - mn);
        float p3 = __expf(v3 - mn);
        ssum = ssum * sc + ((p0 + p1) + (p2 + p3));
        acc.x = acc.x * sc + (p0 * bf2f(u0.x) + p1 * bf2f(u1.x)) + (p2 * bf2f(u2.x) + p3 * bf2f(u3.x));
        acc.y = acc.y * sc + (p0 * bf2f(u0.y) + p1 * bf2f(u1.y)) + (p2 * bf2f(u2.y) + p3 * bf2f(u3.y));
        acc.z = acc.z * sc + (p0 * bf2f(u0.z) + p1 * bf2f(u1.z)) + (p2 * bf2f(u2.z) + p3 * bf2f(u3.z));
        acc.w = acc.w * sc + (p0 * bf2f(u0.w) + p1 * bf2f(u1.w)) + (p2 * bf2f(u2.w) + p3 * bf2f(u3.w));
        m = mn;
    }
    for (; j < je; j++) {
        int s = csr_src[j];
        ushort4 u = *reinterpret_cast<const ushort4*>(&feat16[(size_t)s * 256 + lane * 4]);
        float val = lrelu(el[s * 4 + h] + er_nh);
        float mn = fmaxf(m, val);
        float sc = __expf(m - mn);
        float p = __expf(val - mn);
        ssum = ssum * sc + p;
        acc.x = acc.x * sc + p * bf2f(u.x);
        acc.y = acc.y * sc + p * bf2f(u.y);
        acc.z = acc.z * sc + p * bf2f(u.z);
        acc.w = acc.w * sc + p * bf2f(u.w);
        m = mn;
    }
    float inv = 1.f / fmaxf(ssum, 1e-9f);
    // bias index: h*64 + (lane&15)*4 + i == lane*4 + i
    float4 res;
    res.x = acc.x * inv + bias[lane * 4 + 0];
    res.y = acc.y * inv + bias[lane * 4 + 1];
    res.z = acc.z * inv + bias[lane * 4 + 2];
    res.w = acc.w * inv + bias[lane * 4 + 3];
    if (LAYER == 1) {
        res.x = res.x > 0.f ? res.x : __expf(res.x) - 1.f;
        res.y = res.y > 0.f ? res.y : __expf(res.y) - 1.f;
        res.z = res.z > 0.f ? res.z : __expf(res.z) - 1.f;
        res.w = res.w > 0.f ? res.w : __expf(res.w) - 1.f;
        ushort4 hz, lz;
        hz.x = f2bf(res.x); lz.x = f2bf(res.x - bf2f(hz.x));
        hz.y = f2bf(res.y); lz.y = f2bf(res.y - bf2f(hz.y));
        hz.z = f2bf(res.z); lz.z = f2bf(res.z - bf2f(hz.z));
        hz.w = f2bf(res.w); lz.w = f2bf(res.w - bf2f(hz.w));
        *reinterpret_cast<ushort4*>(&out_hi[(size_t)n * 256 + lane * 4]) = hz;
        *reinterpret_cast<ushort4*>(&out_lo[(size_t)n * 256 + lane * 4]) = lz;
    } else {
        // mean over heads: feature f is held by lanes {f>>2, +16, +32, +48}
#pragma unroll
        for (int mask = 16; mask <= 32; mask <<= 1) {
            res.x += __shfl_xor(res.x, mask, 64);
            res.y += __shfl_xor(res.y, mask, 64);
            res.z += __shfl_xor(res.z, mask, 64);
            res.w += __shfl_xor(res.w, mask, 64);
        }
        if (lane < 16) {
            float4 o = make_float4(res.x * 0.25f, res.y * 0.25f, res.z * 0.25f, res.w * 0.25f);
            *reinterpret_cast<float4*>(&outf[(size_t)n * 64 + lane * 4]) = o;
        }
    }
}

// ---------------- launch ----------------

extern "C" void kernel_launch(void* const* d_in, const int* in_sizes, int n_in,
                              void* d_out, int out_size, void* d_ws, size_t ws_size,
                              hipStream_t stream) {
    const float* features = (const float*)d_in[0];
    const int*   src      = (const int*)d_in[1];
    const int*   dst      = (const int*)d_in[2];
    const float* W1       = (const float*)d_in[3];
    const float* al1      = (const float*)d_in[4];
    const float* ar1      = (const float*)d_in[5];
    const float* b1       = (const float*)d_in[6];
    const float* W2       = (const float*)d_in[7];
    const float* al2      = (const float*)d_in[8];
    const float* ar2      = (const float*)d_in[9];
    const float* b2       = (const float*)d_in[10];
    float* out = (float*)d_out;

    char* ws = (char*)d_ws;
    unsigned short* feat_hi = (unsigned short*)(ws);             // 25,600,000 B [50000x256]
    unsigned short* feat_lo = (unsigned short*)(ws + 25600000);  // 25,600,000 B
    unsigned short* h1_hi   = (unsigned short*)(ws + 51200000);  // 25,600,000 B (union: fA_hi/fA_lo)
    unsigned short* h1_lo   = (unsigned short*)(ws + 76800000);  // 25,600,000 B
    unsigned short* fA_hi   = (unsigned short*)(ws + 51200000);  // 12,800,000 B [50000x128] (dead before h1 written)
    unsigned short* fA_lo   = (unsigned short*)(ws + 64000000);  // 12,800,000 B
    unsigned short* Bt1_hi  = (unsigned short*)(ws + 102400000); //     65,536 B
    unsigned short* Bt1_lo  = (unsigned short*)(ws + 102465536); //     65,536 B
    unsigned short* Bt2_hi  = (unsigned short*)(ws + 102531072); //    131,072 B
    unsigned short* Bt2_lo  = (unsigned short*)(ws + 102662144); //    131,072 B
    float*          el      = (float*)(ws + 102793216);          //    800,000 B
    float*          er      = (float*)(ws + 103593216);          //    800,000 B
    int*            row_off = (int*)  (ws + 104393216);          //    200,064 B
    int*            cur     = (int*)  (ws + 104593280);          //    200,000 B
    int*            csr     = (int*)  (ws + 104793280);          //  3,200,000 B  (end ~108 MB)

    // --- CSR build (graph shared by both layers) ---
    zero_int<<<(N_NODES + 255) / 256, 256, 0, stream>>>(cur, N_NODES);
    hist_kernel<<<(N_EDGES + 255) / 256, 256, 0, stream>>>(dst, cur);
    scan_kernel<<<1, 1024, 0, stream>>>(cur, row_off, N_NODES);
    copy_int<<<(N_NODES + 255) / 256, 256, 0, stream>>>(row_off, cur, N_NODES);
    scatter_kernel<<<(N_EDGES + 255) / 256, 256, 0, stream>>>(src, dst, cur, csr);

    // --- input splits ---
    split_feat<<<(N_NODES * IN_DIM + 255) / 256, 256, 0, stream>>>(features, fA_hi, fA_lo, N_NODES * IN_DIM);
    split_wt<IN_DIM><<<IN_DIM, 256, 0, stream>>>(W1, Bt1_hi, Bt1_lo);
    split_wt<256><<<256, 256, 0, stream>>>(W2, Bt2_hi, Bt2_lo);

    int gemm_blocks = (N_NODES + 63) / 64;   // 782

    // --- layer 1 ---
    mfma_gemm<IN_DIM><<<gemm_blocks, 256, 0, stream>>>(fA_hi, fA_lo, Bt1_hi, Bt1_lo, feat_hi, feat_lo, N_NODES);
    elr_kernel<<<N_NODES, 256, 0, stream>>>(feat_hi, feat_lo, al1, ar1, el, er);
    agg_kernel<1><<<12500, 256, 0, stream>>>(feat_hi, el, er, row_off, csr, b1, h1_hi, h1_lo, nullptr);

    // --- layer 2 ---
    mfma_gemm<256><<<gemm_blocks, 256, 0, stream>>>(h1_hi, h1_lo, Bt2_hi, Bt2_lo, feat_hi, feat_lo, N_NODES);
    elr_kernel<<<N_NODES, 256, 0, stream>>>(feat_hi, feat_lo, al2, ar2, el, er);
    agg_kernel<2><<<12500, 256, 0, stream>>>(feat_hi, el, er, row_off, csr, b2, nullptr, nullptr, out);
}

// Round 7
// 398.468 us; speedup vs baseline: 1.3952x; 1.2021x over previous
//
#include <hip/hip_runtime.h>
#include <hip/hip_bf16.h>
#include <math.h>

#define N_NODES 50000
#define N_EDGES 800000
#define IN_DIM 128
#define NEG_SLOPE 0.2f
// HEADS*HID = HEADS*OUT = 256 columns in both GEMMs

typedef __attribute__((ext_vector_type(8))) short s16x8;
typedef __attribute__((ext_vector_type(4))) float f32x4;

__device__ inline unsigned short f2bf(float v) {   // RNE fp32->bf16
    unsigned u = __float_as_uint(v);
    unsigned r = (u + 0x7fffu + ((u >> 16) & 1u)) >> 16;
    return (unsigned short)r;
}
__device__ inline float bf2f(unsigned short b) {
    return __uint_as_float(((unsigned)b) << 16);
}
__device__ inline float lrelu(float v) {
    return v >= 0.f ? v : NEG_SLOPE * v;
}

// ---------------- CSR build ----------------

__global__ void zero_int(int* __restrict__ p, int n) {
    int i = blockIdx.x * blockDim.x + threadIdx.x;
    if (i < n) p[i] = 0;
}

__global__ void hist_kernel(const int* __restrict__ dst, int* __restrict__ cnt) {
    int e = blockIdx.x * blockDim.x + threadIdx.x;
    if (e < N_EDGES) atomicAdd(&cnt[dst[e]], 1);
}

// single-block scan, wave-shuffle based (2 barriers per 1024-tile)
__global__ __launch_bounds__(1024) void scan_kernel(const int* __restrict__ cnt,
                                                    int* __restrict__ off, int n) {
    __shared__ int wsum[16];
    __shared__ int carry_s;
    int tid = threadIdx.x, wid = tid >> 6, lane = tid & 63;
    if (tid == 0) carry_s = 0;
    __syncthreads();
    for (int base = 0; base < n; base += 1024) {
        int i = base + tid;
        int v = (i < n) ? cnt[i] : 0;
        int x = v;
#pragma unroll
        for (int s = 1; s < 64; s <<= 1) {
            int t = __shfl_up(x, s, 64);
            if (lane >= s) x += t;
        }
        if (lane == 63) wsum[wid] = x;
        __syncthreads();
        if (wid == 0 && lane < 16) {
            int w = wsum[lane];
#pragma unroll
            for (int s = 1; s < 16; s <<= 1) {
                int t = __shfl_up(w, s, 64);
                if (lane >= s) w += t;
            }
            wsum[lane] = w;   // inclusive scan of wave sums
        }
        __syncthreads();
        int woff = (wid > 0) ? wsum[wid - 1] : 0;
        int incl = carry_s + woff + x;
        if (i < n) off[i] = incl - v;   // exclusive
        __syncthreads();
        if (tid == 1023) carry_s = incl;
        __syncthreads();
    }
    if (threadIdx.x == 0) off[n] = carry_s;
}

__global__ void copy_int(const int* __restrict__ a, int* __restrict__ b, int n) {
    int i = blockIdx.x * blockDim.x + threadIdx.x;
    if (i < n) b[i] = a[i];
}

__global__ void scatter_kernel(const int* __restrict__ src, const int* __restrict__ dst,
                               int* __restrict__ cur, int* __restrict__ csr_src) {
    int e = blockIdx.x * blockDim.x + threadIdx.x;
    if (e < N_EDGES) {
        int d = dst[e];
        int pos = atomicAdd(&cur[d], 1);
        csr_src[pos] = src[e];
    }
}

// W [K x 256] fp32 -> Bt hi/lo [256 x K] bf16
template <int K>
__global__ void split_wt(const float* __restrict__ W, unsigned short* __restrict__ Bth,
                         unsigned short* __restrict__ Btl) {
    int k = blockIdx.x;        // 0..K-1
    int c = threadIdx.x;       // 0..255
    float v = W[(size_t)k * 256 + c];
    unsigned short h = f2bf(v);
    Bth[(size_t)c * K + k] = h;
    Btl[(size_t)c * K + k] = f2bf(v - bf2f(h));
}

// ------- MFMA GEMM + fused el/er: C[M,256] = A[M,K]*(Bhi+Blo)[K,256] -------
// Block: 32 rows x 256 cols. 4 waves; wave h = head h's 64-col strip.
// Wave tile 32x64 = 2(mi) x 4(ni) frags of 16x16 (mfma_f32_16x16x32_bf16).
// A: AF32 ? split fp32->hi/lo in regs : load precomputed hi/lo.
// frag: lane l holds row/col (l&15), k = (l>>4)*8 + 0..7 (contiguous 16B).
// C/D: col = lane&15, row = (lane>>4)*4 + reg  (learn_hip m89).
// Epilogue: Chi (bf16) + el/er (exact fp32 acc dotted with attn vecs,
// reduced over the 16-lane col groups via shfl_xor).

template <int K, bool AF32>
__global__ __launch_bounds__(256) void mfma_gemm(const void* __restrict__ A_,
                                                 const unsigned short* __restrict__ Alo,
                                                 const unsigned short* __restrict__ Bth,
                                                 const unsigned short* __restrict__ Btl,
                                                 const float* __restrict__ attl,
                                                 const float* __restrict__ attr,
                                                 unsigned short* __restrict__ Chi,
                                                 float* __restrict__ el,
                                                 float* __restrict__ er,
                                                 int M) {
    int h = threadIdx.x >> 6;          // wave = head / 64-col strip
    int lane = threadIdx.x & 63;
    int r = lane & 15;
    int g = lane >> 4;
    int kg = g * 8;
    int row0 = blockIdx.x * 32;

    f32x4 acc[2][4] = {};              // [mi][ni]

    int rowA0 = row0 + r;      if (rowA0 >= M) rowA0 = M - 1;
    int rowA1 = row0 + 16 + r; if (rowA1 >= M) rowA1 = M - 1;

    const float* Af = (const float*)A_;
    const unsigned short* Ah = (const unsigned short*)A_;
    const unsigned short* pbh = Bth + (size_t)(h * 64 + r) * K + kg;
    const unsigned short* pbl = Btl + (size_t)(h * 64 + r) * K + kg;

#pragma unroll
    for (int kb = 0; kb < K; kb += 32) {
        s16x8 ah0, ah1, al0, al1;
        if (AF32) {
            const float* p0 = Af + (size_t)rowA0 * K + kb + kg;
            const float* p1 = Af + (size_t)rowA1 * K + kb + kg;
            float4 f00 = *reinterpret_cast<const float4*>(p0);
            float4 f01 = *reinterpret_cast<const float4*>(p0 + 4);
            float4 f10 = *reinterpret_cast<const float4*>(p1);
            float4 f11 = *reinterpret_cast<const float4*>(p1 + 4);
            float v0[8] = {f00.x, f00.y, f00.z, f00.w, f01.x, f01.y, f01.z, f01.w};
            float v1[8] = {f10.x, f10.y, f10.z, f10.w, f11.x, f11.y, f11.z, f11.w};
#pragma unroll
            for (int i = 0; i < 8; i++) {
                unsigned short hh0 = f2bf(v0[i]);
                unsigned short hh1 = f2bf(v1[i]);
                ah0[i] = (short)hh0; al0[i] = (short)f2bf(v0[i] - bf2f(hh0));
                ah1[i] = (short)hh1; al1[i] = (short)f2bf(v1[i] - bf2f(hh1));
            }
        } else {
            ah0 = *reinterpret_cast<const s16x8*>(Ah  + (size_t)rowA0 * K + kb + kg);
            ah1 = *reinterpret_cast<const s16x8*>(Ah  + (size_t)rowA1 * K + kb + kg);
            al0 = *reinterpret_cast<const s16x8*>(Alo + (size_t)rowA0 * K + kb + kg);
            al1 = *reinterpret_cast<const s16x8*>(Alo + (size_t)rowA1 * K + kb + kg);
        }
        s16x8 bh[4], bl[4];
#pragma unroll
        for (int ni = 0; ni < 4; ni++) {
            bh[ni] = *reinterpret_cast<const s16x8*>(pbh + (size_t)(ni * 16) * K + kb);
            bl[ni] = *reinterpret_cast<const s16x8*>(pbl + (size_t)(ni * 16) * K + kb);
        }
#pragma unroll
        for (int ni = 0; ni < 4; ni++) {
            acc[0][ni] = __builtin_amdgcn_mfma_f32_16x16x32_bf16(ah0, bh[ni], acc[0][ni], 0, 0, 0);
            acc[1][ni] = __builtin_amdgcn_mfma_f32_16x16x32_bf16(ah1, bh[ni], acc[1][ni], 0, 0, 0);
            acc[0][ni] = __builtin_amdgcn_mfma_f32_16x16x32_bf16(ah0, bl[ni], acc[0][ni], 0, 0, 0);
            acc[1][ni] = __builtin_amdgcn_mfma_f32_16x16x32_bf16(ah1, bl[ni], acc[1][ni], 0, 0, 0);
            acc[0][ni] = __builtin_amdgcn_mfma_f32_16x16x32_bf16(al0, bh[ni], acc[0][ni], 0, 0, 0);
            acc[1][ni] = __builtin_amdgcn_mfma_f32_16x16x32_bf16(al1, bh[ni], acc[1][ni], 0, 0, 0);
        }
    }

    // epilogue: C-write (bf16 hi only) + fused el/er
    float alv[4], arv[4];
#pragma unroll
    for (int ni = 0; ni < 4; ni++) {
        alv[ni] = attl[h * 64 + ni * 16 + r];
        arv[ni] = attr[h * 64 + ni * 16 + r];
    }
#pragma unroll
    for (int mi = 0; mi < 2; mi++) {
#pragma unroll
        for (int reg = 0; reg < 4; reg++) {
            int row = row0 + mi * 16 + g * 4 + reg;
            bool ok = row < M;
            float pel = 0.f, per_ = 0.f;
#pragma unroll
            for (int ni = 0; ni < 4; ni++) {
                float v = acc[mi][ni][reg];
                pel += v * alv[ni];
                per_ += v * arv[ni];
                if (ok) Chi[(size_t)row * 256 + h * 64 + ni * 16 + r] = f2bf(v);
            }
#pragma unroll
            for (int s = 1; s < 16; s <<= 1) {
                pel  += __shfl_xor(pel, s, 64);
                per_ += __shfl_xor(per_, s, 64);
            }
            if (r == 0 && ok) {
                el[row * 4 + h] = pel;
                er[row * 4 + h] = per_;
            }
        }
    }
}

// ------- aggregation: one wave per node, all 4 heads, batch-4 online softmax -------
// lane l holds features l*4..l*4+3 of the 256-wide row; head h = l>>4.
// LAYER 1: writes elu(res) as bf16 hi/lo (input to GEMM2). LAYER 2: head-mean -> fp32 out.

template <int LAYER>
__global__ __launch_bounds__(256) void agg_kernel(const unsigned short* __restrict__ feat16,
                                                  const float* __restrict__ el,
                                                  const float* __restrict__ er,
                                                  const int* __restrict__ row_off,
                                                  const int* __restrict__ csr_src,
                                                  const float* __restrict__ bias,
                                                  unsigned short* __restrict__ out_hi,
                                                  unsigned short* __restrict__ out_lo,
                                                  float* __restrict__ outf) {
    int n = blockIdx.x * 4 + (threadIdx.x >> 6);   // 12500 blocks * 4 waves = 50000
    int lane = threadIdx.x & 63;
    int h = lane >> 4;
    int js = row_off[n], je = row_off[n + 1];
    float er_nh = er[n * 4 + h];
    float m = -INFINITY, ssum = 0.f;
    float4 acc = make_float4(0.f, 0.f, 0.f, 0.f);
    int j = js;
    for (; j + 3 < je; j += 4) {
        int s0 = csr_src[j], s1 = csr_src[j + 1], s2 = csr_src[j + 2], s3 = csr_src[j + 3];
        ushort4 u0 = *reinterpret_cast<const ushort4*>(&feat16[(size_t)s0 * 256 + lane * 4]);
        ushort4 u1 = *reinterpret_cast<const ushort4*>(&feat16[(size_t)s1 * 256 + lane * 4]);
        ushort4 u2 = *reinterpret_cast<const ushort4*>(&feat16[(size_t)s2 * 256 + lane * 4]);
        ushort4 u3 = *reinterpret_cast<const ushort4*>(&feat16[(size_t)s3 * 256 + lane * 4]);
        float v0 = lrelu(el[s0 * 4 + h] + er_nh);
        float v1 = lrelu(el[s1 * 4 + h] + er_nh);
        float v2 = lrelu(el[s2 * 4 + h] + er_nh);
        float v3 = lrelu(el[s3 * 4 + h] + er_nh);
        float mx = fmaxf(fmaxf(v0, v1), fmaxf(v2, v3));
        float mn = fmaxf(m, mx);
        float sc = __expf(m - mn);     // 0 when m == -inf
        float p0 = __expf(v0 - mn);
        float p1 = __expf(v1 - mn);
        float p2 = __expf(v2 - mn);
        float p3 = __expf(v3 - mn);
        ssum = ssum * sc + ((p0 + p1) + (p2 + p3));
        acc.x = acc.x * sc + (p0 * bf2f(u0.x) + p1 * bf2f(u1.x)) + (p2 * bf2f(u2.x) + p3 * bf2f(u3.x));
        acc.y = acc.y * sc + (p0 * bf2f(u0.y) + p1 * bf2f(u1.y)) + (p2 * bf2f(u2.y) + p3 * bf2f(u3.y));
        acc.z = acc.z * sc + (p0 * bf2f(u0.z) + p1 * bf2f(u1.z)) + (p2 * bf2f(u2.z) + p3 * bf2f(u3.z));
        acc.w = acc.w * sc + (p0 * bf2f(u0.w) + p1 * bf2f(u1.w)) + (p2 * bf2f(u2.w) + p3 * bf2f(u3.w));
        m = mn;
    }
    for (; j < je; j++) {
        int s = csr_src[j];
        ushort4 u = *reinterpret_cast<const ushort4*>(&feat16[(size_t)s * 256 + lane * 4]);
        float val = lrelu(el[s * 4 + h] + er_nh);
        float mn = fmaxf(m, val);
        float sc = __expf(m - mn);
        float p = __expf(val - mn);
        ssum = ssum * sc + p;
        acc.x = acc.x * sc + p * bf2f(u.x);
        acc.y = acc.y * sc + p * bf2f(u.y);
        acc.z = acc.z * sc + p * bf2f(u.z);
        acc.w = acc.w * sc + p * bf2f(u.w);
        m = mn;
    }
    float inv = 1.f / fmaxf(ssum, 1e-9f);
    // bias index: h*64 + (lane&15)*4 + i == lane*4 + i
    float4 res;
    res.x = acc.x * inv + bias[lane * 4 + 0];
    res.y = acc.y * inv + bias[lane * 4 + 1];
    res.z = acc.z * inv + bias[lane * 4 + 2];
    res.w = acc.w * inv + bias[lane * 4 + 3];
    if (LAYER == 1) {
        res.x = res.x > 0.f ? res.x : __expf(res.x) - 1.f;
        res.y = res.y > 0.f ? res.y : __expf(res.y) - 1.f;
        res.z = res.z > 0.f ? res.z : __expf(res.z) - 1.f;
        res.w = res.w > 0.f ? res.w : __expf(res.w) - 1.f;
        ushort4 hz, lz;
        hz.x = f2bf(res.x); lz.x = f2bf(res.x - bf2f(hz.x));
        hz.y = f2bf(res.y); lz.y = f2bf(res.y - bf2f(hz.y));
        hz.z = f2bf(res.z); lz.z = f2bf(res.z - bf2f(hz.z));
        hz.w = f2bf(res.w); lz.w = f2bf(res.w - bf2f(hz.w));
        *reinterpret_cast<ushort4*>(&out_hi[(size_t)n * 256 + lane * 4]) = hz;
        *reinterpret_cast<ushort4*>(&out_lo[(size_t)n * 256 + lane * 4]) = lz;
    } else {
        // mean over heads: feature f is held by lanes {f>>2, +16, +32, +48}
#pragma unroll
        for (int mask = 16; mask <= 32; mask <<= 1) {
            res.x += __shfl_xor(res.x, mask, 64);
            res.y += __shfl_xor(res.y, mask, 64);
            res.z += __shfl_xor(res.z, mask, 64);
            res.w += __shfl_xor(res.w, mask, 64);
        }
        if (lane < 16) {
            float4 o = make_float4(res.x * 0.25f, res.y * 0.25f, res.z * 0.25f, res.w * 0.25f);
            *reinterpret_cast<float4*>(&outf[(size_t)n * 64 + lane * 4]) = o;
        }
    }
}

// ---------------- launch ----------------

extern "C" void kernel_launch(void* const* d_in, const int* in_sizes, int n_in,
                              void* d_out, int out_size, void* d_ws, size_t ws_size,
                              hipStream_t stream) {
    const float* features = (const float*)d_in[0];
    const int*   src      = (const int*)d_in[1];
    const int*   dst      = (const int*)d_in[2];
    const float* W1       = (const float*)d_in[3];
    const float* al1      = (const float*)d_in[4];
    const float* ar1      = (const float*)d_in[5];
    const float* b1       = (const float*)d_in[6];
    const float* W2       = (const float*)d_in[7];
    const float* al2      = (const float*)d_in[8];
    const float* ar2      = (const float*)d_in[9];
    const float* b2       = (const float*)d_in[10];
    float* out = (float*)d_out;

    char* ws = (char*)d_ws;
    unsigned short* feat16  = (unsigned short*)(ws);             // 25,600,000 B [50000x256]
    unsigned short* h1_hi   = (unsigned short*)(ws + 25600000);  // 25,600,000 B
    unsigned short* h1_lo   = (unsigned short*)(ws + 51200000);  // 25,600,000 B
    unsigned short* Bt1_hi  = (unsigned short*)(ws + 76800000);  //     65,536 B
    unsigned short* Bt1_lo  = (unsigned short*)(ws + 76865536);  //     65,536 B
    unsigned short* Bt2_hi  = (unsigned short*)(ws + 76931072);  //    131,072 B
    unsigned short* Bt2_lo  = (unsigned short*)(ws + 77062144);  //    131,072 B
    float*          el      = (float*)(ws + 77193216);           //    800,000 B
    float*          er      = (float*)(ws + 77993216);           //    800,000 B
    int*            row_off = (int*)  (ws + 78793216);           //    200,064 B
    int*            cur     = (int*)  (ws + 78993280);           //    200,000 B
    int*            csr     = (int*)  (ws + 79193280);           //  3,200,000 B  (end ~82.4 MB)

    // --- CSR build (graph shared by both layers) ---
    zero_int<<<(N_NODES + 255) / 256, 256, 0, stream>>>(cur, N_NODES);
    hist_kernel<<<(N_EDGES + 255) / 256, 256, 0, stream>>>(dst, cur);
    scan_kernel<<<1, 1024, 0, stream>>>(cur, row_off, N_NODES);
    copy_int<<<(N_NODES + 255) / 256, 256, 0, stream>>>(row_off, cur, N_NODES);
    scatter_kernel<<<(N_EDGES + 255) / 256, 256, 0, stream>>>(src, dst, cur, csr);

    // --- weight splits ---
    split_wt<IN_DIM><<<IN_DIM, 256, 0, stream>>>(W1, Bt1_hi, Bt1_lo);
    split_wt<256><<<256, 256, 0, stream>>>(W2, Bt2_hi, Bt2_lo);

    int gemm_blocks = (N_NODES + 31) / 32;   // 1563

    // --- layer 1 (A = fp32 features, split in-kernel) ---
    mfma_gemm<IN_DIM, true><<<gemm_blocks, 256, 0, stream>>>(
        features, nullptr, Bt1_hi, Bt1_lo, al1, ar1, feat16, el, er, N_NODES);
    agg_kernel<1><<<12500, 256, 0, stream>>>(feat16, el, er, row_off, csr, b1, h1_hi, h1_lo, nullptr);

    // --- layer 2 (A = h1 hi/lo bf16) ---
    mfma_gemm<256, false><<<gemm_blocks, 256, 0, stream>>>(
        h1_hi, h1_lo, Bt2_hi, Bt2_lo, al2, ar2, feat16, el, er, N_NODES);
    agg_kernel<2><<<12500, 256, 0, stream>>>(feat16, el, er, row_off, csr, b2, nullptr, nullptr, out);
}